// Round 3
// baseline (613.419 us; speedup 1.0000x reference)
//
#include <hip/hip_runtime.h>
#include <hip/hip_bf16.h>
#include <math.h>

typedef __bf16 bfx8 __attribute__((ext_vector_type(8)));
typedef float f32x4 __attribute__((ext_vector_type(4)));
typedef float f32x16 __attribute__((ext_vector_type(16)));
typedef unsigned short u16x8 __attribute__((ext_vector_type(8)));

#define NELEM_W 36864
#define CHW     50176          // 224*224
#define XB_ROWPITCH 28928      // 226 cols * 64 ic * 2B
#define XB_BYTES (16*224*XB_ROWPITCH)   // 103,694,336
#define ZP_OFF   81920
#define XB_OFF   98304
#define WS_NEED  ((size_t)XB_OFF + (size_t)XB_BYTES)

__device__ __forceinline__ void async_cp16(const void* g, void* l) {
  __builtin_amdgcn_global_load_lds(
      (const __attribute__((address_space(1))) unsigned int*)g,
      (__attribute__((address_space(3))) unsigned int*)l, 16, 0, 0);
}

// ---------- mask dtype detection ----------
__device__ __forceinline__ int detect_mask_kind(const void* mask, int tid, int nthreads,
                                                int* s_flags, int* s_kind) {
  if (tid < 8) s_flags[tid] = 0;
  __syncthreads();
  const unsigned int* mw = (const unsigned int*)mask;
  int lowbf = 0, notf32 = 0, anyf32 = 0, noti32 = 0, anyi1 = 0;
  for (int i = tid; i < 1024; i += nthreads) {
    unsigned v = mw[i];
    if ((v & 0xFFFFu) == 0x3F80u) lowbf = 1;
    if (!(v == 0u || v == 0x3F800000u)) notf32 = 1;
    if (v == 0x3F800000u) anyf32 = 1;
    if (!(v == 0u || v == 1u)) noti32 = 1;
    if (v == 1u) anyi1 = 1;
  }
  if (lowbf)  atomicOr(&s_flags[0], 1);
  if (notf32) atomicOr(&s_flags[1], 1);
  if (anyf32) atomicOr(&s_flags[2], 1);
  if (noti32) atomicOr(&s_flags[3], 1);
  if (anyi1)  atomicOr(&s_flags[4], 1);
  __syncthreads();
  if (tid == 0) {
    int kind;
    if (s_flags[0]) kind = 3;
    else if (!s_flags[1] && s_flags[2]) kind = 2;
    else if (!s_flags[3] && s_flags[4]) kind = 1;
    else kind = 0;
    *s_kind = kind;
  }
  __syncthreads();
  return *s_kind;
}

__device__ __forceinline__ bool mask_val(const void* mask, int kind, int e) {
  switch (kind) {
    case 1:  return ((const int*)mask)[e] != 0;
    case 2:  return ((const float*)mask)[e] != 0.0f;
    case 3:  return ((const unsigned short*)mask)[e] != 0;
    default: return ((const unsigned char*)mask)[e] != 0;
  }
}

// ---------- k1: deterministic masked stats ----------
__global__ __launch_bounds__(512) void stats_kernel(const float* __restrict__ W,
                                                    const void* __restrict__ mask,
                                                    float* __restrict__ ws_part) {
  __shared__ int s_flags[8]; __shared__ int s_kind;
  __shared__ float s_red[3][8];
  const int tid = threadIdx.x;
  int kind = detect_mask_kind(mask, tid, 512, s_flags, &s_kind);
  int e = blockIdx.x * 512 + tid;
  float w = W[e];
  bool m = mask_val(mask, kind, e);
  float s1 = m ? fabsf(w) : 0.f;
  float s2 = m ? w * w   : 0.f;
  float c  = m ? 1.f     : 0.f;
  #pragma unroll
  for (int o = 32; o > 0; o >>= 1) {
    s1 += __shfl_down(s1, o); s2 += __shfl_down(s2, o); c += __shfl_down(c, o);
  }
  int wv = tid >> 6;
  if ((tid & 63) == 0) { s_red[0][wv] = s1; s_red[1][wv] = s2; s_red[2][wv] = c; }
  __syncthreads();
  if (tid == 0) {
    float a = 0, b = 0, cc = 0;
    for (int i = 0; i < 8; i++) { a += s_red[0][i]; b += s_red[1][i]; cc += s_red[2][i]; }
    ws_part[blockIdx.x * 4 + 0] = a;
    ws_part[blockIdx.x * 4 + 1] = b;
    ws_part[blockIdx.x * 4 + 2] = cc;
  }
}

// ---------- k2: finalize scale + quantize W into Bq[kykx][oc][ic]; block 72 zeros the zero-page ----------
__global__ __launch_bounds__(512) void quant_kernel(const float* __restrict__ W,
                                                    const void* __restrict__ mask,
                                                    const float* __restrict__ ws_part,
                                                    float* __restrict__ ws_scale,
                                                    unsigned short* __restrict__ Bq,
                                                    char* __restrict__ zp) {
  __shared__ int s_flags[8]; __shared__ int s_kind;
  __shared__ float s_scale;
  const int tid = threadIdx.x;
  int kind = detect_mask_kind(mask, tid, 512, s_flags, &s_kind);
  if (tid == 0) {
    float a = 0, b = 0, cc = 0;
    for (int i = 0; i < 72; i++) { a += ws_part[i*4]; b += ws_part[i*4+1]; cc += ws_part[i*4+2]; }
    float n  = fmaxf(cc, 1.f);
    float m1 = a / n, m2 = b / n;
    float alpha = 12.68f * sqrtf(m2) - 12.80f * m1;
    float scale = alpha / 127.0f;
    s_scale = scale;
    if (blockIdx.x == 0) ws_scale[0] = scale;
  }
  __syncthreads();
  float scale = s_scale;
  int e = blockIdx.x * 512 + tid;
  if (e < NELEM_W) {
    float w = W[e];
    float q = 0.f;
    if (mask_val(mask, kind, e)) {
      float v = w / scale;
      v = fminf(fmaxf(v, -127.f), 127.f);
      q = rintf(v);
    }
    int kxy = e % 9; int t = e / 9; int ic = t & 63; int oc = t >> 6;
    __bf16 qb = (__bf16)q;
    Bq[(kxy * 64 + oc) * 64 + ic] = *(unsigned short*)&qb;
  } else {
    // block 72: zero-page (8448 B) used as halo-row source for global_load_lds
    f32x4 z = {0.f, 0.f, 0.f, 0.f};
    for (int u = tid; u < 528; u += 512) *(f32x4*)(zp + u * 16) = z;
  }
}

// ---------- pre-pass: x NCHW f32 -> xb padded NHWC bf16 [b][h][226][64ic], pre-XOR-swizzled ----------
__global__ __launch_bounds__(256) void prepass_kernel(const float* __restrict__ x,
                                                      char* __restrict__ xb) {
  __shared__ unsigned short lt[64][65];   // [ic][col], pitch 65 vs bank conflicts
  const int cg = blockIdx.x;              // col-group 0..3 (64 padded cols each)
  const int h  = blockIdx.y;
  const int b  = blockIdx.z;
  const int t  = threadIdx.x;
  const int c0 = cg * 64;
  const int ncols = (226 - c0) < 64 ? (226 - c0) : 64;   // 64,64,64,34

  {  // phase 1: coalesced read (lanes = cols), cvt, LDS [ic][col]
    int colt = t & 63, icq = t >> 6;      // icq handles 16 ic
    if (colt < ncols) {
      int gcol = c0 + colt - 1;
      bool valid = (unsigned)gcol < 224u;
      const float* src = x + ((size_t)(b * 64 + icq * 16) * 224 + h) * 224 + gcol;
      #pragma unroll
      for (int j = 0; j < 16; j++) {
        float v = valid ? src[(size_t)j * CHW] : 0.f;
        __bf16 bv = (__bf16)v;
        lt[icq * 16 + j][colt] = *(unsigned short*)&bv;
      }
    }
  }
  __syncthreads();
  // phase 2: write 16B units [col][ic 8-group], XOR-swizzled byte layout
  size_t rowbase = ((size_t)(b * 224 + h)) * XB_ROWPITCH;
  for (int u = t; u < ncols * 8; u += 256) {
    int colt = u >> 3, icg = u & 7;
    int c = c0 + colt;
    u16x8 v;
    #pragma unroll
    for (int j = 0; j < 8; j++) v[j] = lt[icg * 8 + j][colt];
    int off = (c * 128 + icg * 16) ^ ((c & 7) << 4);
    *(u16x8*)(xb + rowbase + off) = v;
  }
}

// ---------- conv: async-staged, mfma_f32_32x32x16_bf16 ----------
// LDS 6 rows x 66 cols x 64 ic bf16 = 50688 B -> 3 blocks/CU.
// 8 waves = 4 rows x 2 col-halves; per wave: 2 oc-tiles (0..31,32..63) x 32 cols.
__global__ __launch_bounds__(512, 6) void conv_kernel(const char* __restrict__ xb,
    const char* __restrict__ zp, const unsigned short* __restrict__ Bq,
    const float* __restrict__ ws_scale, const float* __restrict__ bias,
    float* __restrict__ out)
{
  __shared__ __align__(16) unsigned char smem[6 * 66 * 128];  // 50688 B
  const int tid = threadIdx.x;

  int lin = blockIdx.x + (int)(gridDim.x * (blockIdx.y + gridDim.y * blockIdx.z));
  int logical = (lin & 7) * 448 + (lin >> 3);     // bijective: 3584 % 8 == 0
  const int bx = logical & 3;
  int rr = logical >> 2;
  const int by = rr % 56;
  const int b  = rr / 56;
  const int x0 = bx * 64;
  const int y0 = by * 4;

  const int w = tid >> 6, lane = tid & 63;

  // ---- staging: 48 full 1024B chunks via global_load_lds (wave-uniform LDS dest) ----
  {
    const size_t winoff = (size_t)x0 * 128;       // window start in padded row
    #pragma unroll
    for (int j = w; j < 48; j += 8) {
      int row = j >> 3, chunk = j & 7;
      int grow = y0 - 1 + row;
      const char* src = ((unsigned)grow < 224u)
          ? xb + ((size_t)(b * 224 + grow)) * XB_ROWPITCH + winoff + chunk * 1024
          : zp + chunk * 1024;
      async_cp16(src + lane * 16, smem + row * 8448 + chunk * 1024);
    }
    // tail: last 256 B of each row (cols 64,65)
    if (tid < 96) {
      int row = tid >> 4, u = tid & 15;
      int grow = y0 - 1 + row;
      const char* src = ((unsigned)grow < 224u)
          ? xb + ((size_t)(b * 224 + grow)) * XB_ROWPITCH + winoff + 8192 + u * 16
          : zp + 8192 + u * 16;
      *(f32x4*)(smem + row * 8448 + 8192 + u * 16) = *(const f32x4*)src;
    }
  }
  __syncthreads();

  // ---- compute: 32x32x16 MFMA; wave = (row, col-half); both oc-tiles share B-frag ----
  const int wrow = w >> 1;            // 0..3
  const int ch   = w & 1;             // col half
  const int l31  = lane & 31, lg2 = lane >> 5;

  f32x16 acc0 = {}, acc1 = {};

  #pragma unroll
  for (int ky = 0; ky < 3; ky++) {
    const int lrow = wrow + ky;
    #pragma unroll
    for (int kx = 0; kx < 3; kx++) {
      const int kxy = ky * 3 + kx;
      #pragma unroll
      for (int icq = 0; icq < 4; icq++) {
        const int ick = icq * 16 + lg2 * 8;       // 8 contiguous ic, k=(lane>>5)*8+j
        // B: x[ic][col], col = l31
        const int ct  = kx + ch * 32 + l31;
        const int off = (lrow * 66 + ct) * 128 + ((ick * 2) ^ ((ct & 7) << 4));
        bfx8 xf = *(const bfx8*)(smem + off);
        // A: q[oc][ic], oc row = l31
        const unsigned short* wp = Bq + ((kxy * 64 + l31) * 64 + ick);
        bfx8 wf0 = *(const bfx8*)wp;
        bfx8 wf1 = *(const bfx8*)(wp + 32 * 64);
        acc0 = __builtin_amdgcn_mfma_f32_32x32x16_bf16(wf0, xf, acc0, 0, 0, 0);
        acc1 = __builtin_amdgcn_mfma_f32_32x32x16_bf16(wf1, xf, acc1, 0, 0, 0);
      }
    }
  }

  const float scale = ws_scale[0];
  const int yr = y0 + wrow;
  const int gcol = x0 + ch * 32 + l31;
  if (gcol < 224) {
    #pragma unroll
    for (int r = 0; r < 16; r++) {
      int ocr = (r & 3) + 8 * (r >> 2) + 4 * lg2;  // C/D: row=(reg&3)+8*(reg>>2)+4*(lane>>5)
      size_t o0 = (((size_t)(b * 64 + ocr)) * 224 + yr) * 224 + gcol;
      out[o0]              = acc0[r] * scale + bias[ocr];
      out[o0 + 32 * CHW]   = acc1[r] * scale + bias[ocr + 32];
    }
  }
}

// ---------- fallback conv (round-2 verified path) if ws_size too small ----------
__global__ __launch_bounds__(512, 6) void conv_fallback(const float* __restrict__ x,
    const unsigned short* __restrict__ Bq, const float* __restrict__ ws_scale,
    const float* __restrict__ bias, float* __restrict__ out)
{
  __shared__ __align__(16) unsigned char smem[6 * 66 * 128];
  const int tid = threadIdx.x;
  int lin = blockIdx.x + (int)(gridDim.x * (blockIdx.y + gridDim.y * blockIdx.z));
  int logical = (lin & 7) * 448 + (lin >> 3);
  const int bx = logical & 3;
  int rr = logical >> 2;
  const int by = rr % 56;
  const int b  = rr / 56;
  const int x0 = bx * 64;
  const int y0 = by * 4;

  for (int e = tid; e < 6 * 8 * 66; e += 512) {
    int col = e % 66; int t = e / 66; int icg = t & 7; int row = t >> 3;
    int grow = y0 - 1 + row, gcol = x0 - 1 + col;
    bfx8 v;
    if ((unsigned)grow < 224u && (unsigned)gcol < 224u) {
      const float* src = x + (((size_t)(b * 64 + icg * 8)) * 224 + grow) * 224 + gcol;
      #pragma unroll
      for (int j = 0; j < 8; j++) v[j] = (__bf16)src[j * CHW];
    } else {
      #pragma unroll
      for (int j = 0; j < 8; j++) v[j] = (__bf16)0.f;
    }
    int off = ((row * 66 + col) * 128 + icg * 16) ^ ((col & 7) << 4);
    *(bfx8*)(smem + off) = v;
  }
  __syncthreads();

  const int w = tid >> 6, lane = tid & 63;
  const int l15 = lane & 15, lg = lane >> 4;
  const int wrow = w >> 1;
  const int oc0  = (w & 1) * 32;

  f32x4 acc[4][2];
  #pragma unroll
  for (int m = 0; m < 4; m++) { acc[m][0] = {0.f,0.f,0.f,0.f}; acc[m][1] = {0.f,0.f,0.f,0.f}; }
  #pragma unroll
  for (int ky = 0; ky < 3; ky++) {
    const int lrow = wrow + ky;
    #pragma unroll
    for (int kx = 0; kx < 3; kx++) {
      #pragma unroll
      for (int icb = 0; icb < 2; icb++) {
        const int ick = icb * 32 + lg * 8;
        const unsigned short* wp = Bq + (((ky*3 + kx) * 64 + oc0 + l15) * 64 + ick);
        bfx8 wf0 = *(const bfx8*)wp;
        bfx8 wf1 = *(const bfx8*)(wp + 16 * 64);
        #pragma unroll
        for (int m = 0; m < 4; m++) {
          int colw = kx + m * 16 + l15;
          int off  = ((lrow * 66 + colw) * 128 + ick * 2) ^ ((colw & 7) << 4);
          bfx8 xf  = *(const bfx8*)(smem + off);
          acc[m][0] = __builtin_amdgcn_mfma_f32_16x16x32_bf16(wf0, xf, acc[m][0], 0, 0, 0);
          acc[m][1] = __builtin_amdgcn_mfma_f32_16x16x32_bf16(wf1, xf, acc[m][1], 0, 0, 0);
        }
      }
    }
  }
  const float scale = ws_scale[0];
  const int yr = y0 + wrow;
  #pragma unroll
  for (int m = 0; m < 4; m++) {
    const int gcol = x0 + m * 16 + l15;
    if (gcol < 224) {
      #pragma unroll
      for (int n = 0; n < 2; n++) {
        #pragma unroll
        for (int r = 0; r < 4; r++) {
          int oc = oc0 + n * 16 + lg * 4 + r;
          out[(((size_t)(b * 64 + oc)) * 224 + yr) * 224 + gcol] = acc[m][n][r] * scale + bias[oc];
        }
      }
    }
  }
}

extern "C" void kernel_launch(void* const* d_in, const int* in_sizes, int n_in,
                              void* d_out, int out_size, void* d_ws, size_t ws_size,
                              hipStream_t stream) {
  const float* x    = (const float*)d_in[0];
  const float* W    = (const float*)d_in[1];
  const void*  mask = d_in[2];
  const float* bias = (const float*)d_in[3];
  float* out = (float*)d_out;

  float*          ws_part  = (float*)d_ws;
  float*          ws_scale = (float*)((char*)d_ws + 2048);
  unsigned short* Bq       = (unsigned short*)((char*)d_ws + 4096);
  char*           zp       = (char*)d_ws + ZP_OFF;
  char*           xb       = (char*)d_ws + XB_OFF;

  stats_kernel<<<72, 512, 0, stream>>>(W, mask, ws_part);
  quant_kernel<<<73, 512, 0, stream>>>(W, mask, ws_part, ws_scale, Bq, zp);

  dim3 cgrid(4, 56, 16);
  if (ws_size >= WS_NEED) {
    dim3 pgrid(4, 224, 16);
    prepass_kernel<<<pgrid, 256, 0, stream>>>(x, xb);
    conv_kernel<<<cgrid, 512, 0, stream>>>(xb, zp, Bq, ws_scale, bias, out);
  } else {
    conv_fallback<<<cgrid, 512, 0, stream>>>(x, Bq, ws_scale, bias, out);
  }
}